// Round 1
// baseline (1397.716 us; speedup 1.0000x reference)
//
#include <hip/hip_runtime.h>
#include <math.h>

// Problem constants
constexpr int kB    = 64;
constexpr int kN    = 32;
constexpr int kDIN  = 128;
constexpr int kH    = 256;
constexpr int kG4   = 1024;   // 4*H
constexpr int kDOUT = 128;
constexpr int kBN   = 2048;   // B*N

__device__ __forceinline__ float sigm(float x) {
    return 1.0f / (1.0f + expf(-x));
}

// ---------------------------------------------------------------------------
// K0: generic 32x32 tiled transpose  dst[C][R] = src[R][C]
// block dim3(32,8); grid (C/32, R/32). R,C multiples of 32 here.
// ---------------------------------------------------------------------------
__global__ __launch_bounds__(256) void transpose_k(
    const float* __restrict__ src, float* __restrict__ dst, int R, int C)
{
    __shared__ float tile[32][33];
    const int c0 = blockIdx.x * 32;
    const int r0 = blockIdx.y * 32;
    const int tx = threadIdx.x;
    const int ty = threadIdx.y;
    #pragma unroll
    for (int i = ty; i < 32; i += 8)
        tile[i][tx] = src[(size_t)(r0 + i) * C + (c0 + tx)];
    __syncthreads();
    #pragma unroll
    for (int i = ty; i < 32; i += 8)
        dst[(size_t)(c0 + i) * R + (r0 + tx)] = tile[tx][i];
}

// ---------------------------------------------------------------------------
// K1: xW_d[(b,t)][gate] = x[b,t,:] @ W_ih_d.T   (no bias, no mask yet)
// Inputs pre-transposed: WihT[k][gate].
// grid 256 blocks, 8 rows each; 256 threads; thread -> 4 gates both dirs.
// ---------------------------------------------------------------------------
__global__ __launch_bounds__(256) void k1_xw(
    const float* __restrict__ x,
    const float* __restrict__ WihT_f, const float* __restrict__ WihT_r,
    float* __restrict__ xW_f, float* __restrict__ xW_r)
{
    __shared__ float xs[8 * kDIN];   // 4 KB
    const int tid = threadIdx.x;
    const int r0  = blockIdx.x * 8;
    const int gi  = tid * 4;

    // cooperative load of 8 x-rows (1024 floats = 256 float4)
    ((float4*)xs)[tid] = ((const float4*)(x + (size_t)r0 * kDIN))[tid];
    __syncthreads();

    float accf[8][4], accr[8][4];
    #pragma unroll
    for (int s = 0; s < 8; ++s)
        #pragma unroll
        for (int q = 0; q < 4; ++q) { accf[s][q] = 0.f; accr[s][q] = 0.f; }

    #pragma unroll 2
    for (int k = 0; k < kDIN; ++k) {
        float4 wf = *(const float4*)(WihT_f + (size_t)k * kG4 + gi);
        float4 wr = *(const float4*)(WihT_r + (size_t)k * kG4 + gi);
        float wfa[4] = {wf.x, wf.y, wf.z, wf.w};
        float wra[4] = {wr.x, wr.y, wr.z, wr.w};
        #pragma unroll
        for (int s = 0; s < 8; ++s) {
            float xv = xs[s * kDIN + k];
            #pragma unroll
            for (int q = 0; q < 4; ++q) {
                accf[s][q] = fmaf(xv, wfa[q], accf[s][q]);
                accr[s][q] = fmaf(xv, wra[q], accr[s][q]);
            }
        }
    }

    #pragma unroll
    for (int s = 0; s < 8; ++s) {
        float4 vf = make_float4(accf[s][0], accf[s][1], accf[s][2], accf[s][3]);
        float4 vr = make_float4(accr[s][0], accr[s][1], accr[s][2], accr[s][3]);
        *(float4*)(xW_f + (size_t)(r0 + s) * kG4 + gi) = vf;
        *(float4*)(xW_r + (size_t)(r0 + s) * kG4 + gi) = vr;
    }
}

// ---------------------------------------------------------------------------
// K2: bidirectional LSTM recurrence, diagonal extraction.
// Block = (n, batch-tile of 8). Runs forward n+1 steps then reverse 32-n
// steps (33 total, uniform across blocks). h in LDS; gates staged through
// LDS for the per-hidden-unit activation update.
// y[(b*32+n)*512 + dir*256 + j] = h_dir[t=n][b,n][j]
// ---------------------------------------------------------------------------
__global__ __launch_bounds__(256) void k2_lstm(
    const float* __restrict__ mask,
    const float* __restrict__ xW_f, const float* __restrict__ xW_r,
    const float* __restrict__ WT_f, const float* __restrict__ WT_r,
    const float* __restrict__ b_f,  const float* __restrict__ b_r,
    float* __restrict__ y)
{
    __shared__ float h_lds[8 * kH];    // 8 KB
    __shared__ float g_lds[8 * kG4];   // 32 KB

    const int tid = threadIdx.x;
    const int n   = blockIdx.x >> 3;         // 0..31
    const int b0  = (blockIdx.x & 7) * 8;    // batch base
    const int gi  = tid * 4;                 // gate base for GEMM phase

    for (int dir = 0; dir < 2; ++dir) {
        const float* __restrict__ xW = dir ? xW_r : xW_f;
        const float* __restrict__ WT = dir ? WT_r : WT_f;
        const float* __restrict__ bb = dir ? b_r  : b_f;
        const float4 bias = *(const float4*)(bb + gi);

        // zero state
        for (int i = tid; i < 8 * kH; i += 256) h_lds[i] = 0.f;
        float c[8];
        #pragma unroll
        for (int s = 0; s < 8; ++s) c[s] = 0.f;
        __syncthreads();

        const int nsteps = dir ? (kN - n) : (n + 1);
        for (int it = 0; it < nsteps; ++it) {
            const int t = dir ? (kN - 1 - it) : it;

            // ---- GEMM phase: g = mask * xW + bias + h @ W_hh.T ----
            float acc[8][4];
            #pragma unroll
            for (int s = 0; s < 8; ++s) {
                const int   row = (b0 + s) * kN + t;
                const float m   = mask[(size_t)(b0 + s) * (kN * kN) + n * kN + t];
                float4 xv = *(const float4*)(xW + (size_t)row * kG4 + gi);
                acc[s][0] = fmaf(m, xv.x, bias.x);
                acc[s][1] = fmaf(m, xv.y, bias.y);
                acc[s][2] = fmaf(m, xv.z, bias.z);
                acc[s][3] = fmaf(m, xv.w, bias.w);
            }

            #pragma unroll 2
            for (int k0 = 0; k0 < kH; k0 += 4) {
                float w[4][4];
                #pragma unroll
                for (int kk = 0; kk < 4; ++kk) {
                    float4 wv = *(const float4*)(WT + (size_t)(k0 + kk) * kG4 + gi);
                    w[kk][0] = wv.x; w[kk][1] = wv.y; w[kk][2] = wv.z; w[kk][3] = wv.w;
                }
                #pragma unroll
                for (int s = 0; s < 8; ++s) {
                    float4 hvv = *(const float4*)(h_lds + s * kH + k0);
                    float hv[4] = {hvv.x, hvv.y, hvv.z, hvv.w};
                    #pragma unroll
                    for (int kk = 0; kk < 4; ++kk)
                        #pragma unroll
                        for (int q = 0; q < 4; ++q)
                            acc[s][q] = fmaf(hv[kk], w[kk][q], acc[s][q]);
                }
            }

            #pragma unroll
            for (int s = 0; s < 8; ++s)
                *(float4*)(g_lds + s * kG4 + gi) =
                    make_float4(acc[s][0], acc[s][1], acc[s][2], acc[s][3]);
            __syncthreads();

            // ---- update phase: thread = hidden unit tid, all 8 seqs ----
            #pragma unroll
            for (int s = 0; s < 8; ++s) {
                const float gI = g_lds[s * kG4 + tid];
                const float gF = g_lds[s * kG4 + kH + tid];
                const float gG = g_lds[s * kG4 + 2 * kH + tid];
                const float gO = g_lds[s * kG4 + 3 * kH + tid];
                const float ct = sigm(gF) * c[s] + sigm(gI) * tanhf(gG);
                c[s] = ct;
                const float hn = sigm(gO) * tanhf(ct);
                h_lds[s * kH + tid] = hn;
                if (t == n)
                    y[((size_t)(b0 + s) * kN + n) * (2 * kH) + dir * kH + tid] = hn;
            }
            __syncthreads();
        }
        __syncthreads();
    }
}

// ---------------------------------------------------------------------------
// K3: out = relu(y @ W_fc.T + b_fc).  WfcT[k][dout] pre-transposed.
// grid 256 blocks x 8 rows; 256 threads: col = tid&127, row-half = tid>>7.
// ---------------------------------------------------------------------------
__global__ __launch_bounds__(256) void k3_out(
    const float* __restrict__ y, const float* __restrict__ WfcT,
    const float* __restrict__ b_fc, float* __restrict__ out)
{
    __shared__ float ys[8 * 2 * kH];   // 16 KB
    const int tid = threadIdx.x;
    const int r0  = blockIdx.x * 8;
    const int col = tid & 127;
    const int rh  = tid >> 7;

    for (int i = tid; i < 8 * 2 * kH / 4; i += 256)
        ((float4*)ys)[i] = ((const float4*)(y + (size_t)r0 * (2 * kH)))[i];
    __syncthreads();

    float acc[4] = {0.f, 0.f, 0.f, 0.f};
    #pragma unroll 4
    for (int k = 0; k < 2 * kH; ++k) {
        const float w = WfcT[(size_t)k * kDOUT + col];
        #pragma unroll
        for (int j = 0; j < 4; ++j)
            acc[j] = fmaf(ys[(rh * 4 + j) * (2 * kH) + k], w, acc[j]);
    }

    const float bias = b_fc[col];
    #pragma unroll
    for (int j = 0; j < 4; ++j) {
        const int row = r0 + rh * 4 + j;
        out[(size_t)row * kDOUT + col] = fmaxf(acc[j] + bias, 0.f);
    }
}

// ---------------------------------------------------------------------------
extern "C" void kernel_launch(void* const* d_in, const int* in_sizes, int n_in,
                              void* d_out, int out_size, void* d_ws, size_t ws_size,
                              hipStream_t stream) {
    const float* x      = (const float*)d_in[0];
    const float* mask   = (const float*)d_in[1];
    const float* W_ih_f = (const float*)d_in[2];
    const float* W_hh_f = (const float*)d_in[3];
    const float* b_f    = (const float*)d_in[4];
    const float* W_ih_r = (const float*)d_in[5];
    const float* W_hh_r = (const float*)d_in[6];
    const float* b_r    = (const float*)d_in[7];
    const float* W_fc   = (const float*)d_in[8];
    const float* b_fc   = (const float*)d_in[9];
    float* out = (float*)d_out;

    float* ws     = (float*)d_ws;
    float* WihT_f = ws;                    // 128*1024
    float* WihT_r = WihT_f + 131072;       // 128*1024
    float* WT_f   = WihT_r + 131072;       // 256*1024
    float* WT_r   = WT_f   + 262144;       // 256*1024
    float* WfcT   = WT_r   + 262144;       // 512*128
    float* xW_f   = WfcT   + 65536;        // 2048*1024
    float* xW_r   = xW_f   + 2097152;      // 2048*1024
    float* yb     = xW_r   + 2097152;      // 2048*512

    dim3 tb(32, 8);
    transpose_k<<<dim3(kDIN / 32, kG4 / 32), tb, 0, stream>>>(W_ih_f, WihT_f, kG4, kDIN);
    transpose_k<<<dim3(kDIN / 32, kG4 / 32), tb, 0, stream>>>(W_ih_r, WihT_r, kG4, kDIN);
    transpose_k<<<dim3(kH / 32, kG4 / 32),  tb, 0, stream>>>(W_hh_f, WT_f, kG4, kH);
    transpose_k<<<dim3(kH / 32, kG4 / 32),  tb, 0, stream>>>(W_hh_r, WT_r, kG4, kH);
    transpose_k<<<dim3(2 * kH / 32, kDOUT / 32), tb, 0, stream>>>(W_fc, WfcT, kDOUT, 2 * kH);

    k1_xw<<<kBN / 8, 256, 0, stream>>>(x, WihT_f, WihT_r, xW_f, xW_r);
    k2_lstm<<<kN * 8, 256, 0, stream>>>(mask, xW_f, xW_r, WT_f, WT_r, b_f, b_r, yb);
    k3_out<<<kBN / 8, 256, 0, stream>>>(yb, WfcT, b_fc, out);
}

// Round 2
// 789.726 us; speedup vs baseline: 1.7699x; 1.7699x over previous
//
#include <hip/hip_runtime.h>
#include <math.h>

// Problem constants
constexpr int kB    = 64;
constexpr int kN    = 32;
constexpr int kDIN  = 128;
constexpr int kH    = 256;
constexpr int kG4   = 1024;   // 4*H
constexpr int kDOUT = 128;
constexpr int kBN   = 2048;   // B*N

__device__ __forceinline__ float sigm(float x) {
    return 1.0f / (1.0f + expf(-x));
}

// ---------------------------------------------------------------------------
// K0: all 5 weight transposes in ONE launch. dst[C][R] = src[R][C].
// Segments (32x32 tiles, dim3(32,8) threads):
//   seg0 W_ih_f 1024x128 -> 128 tiles   [0,128)
//   seg1 W_ih_r 1024x128 -> 128 tiles   [128,256)
//   seg2 W_hh_f 1024x256 -> 256 tiles   [256,512)
//   seg3 W_hh_r 1024x256 -> 256 tiles   [512,768)
//   seg4 W_fc   128x512  -> 64 tiles    [768,832)
// ---------------------------------------------------------------------------
__global__ __launch_bounds__(256) void prep_transpose(
    const float* __restrict__ Wihf, const float* __restrict__ Wihr,
    const float* __restrict__ Whhf, const float* __restrict__ Whhr,
    const float* __restrict__ Wfc,
    float* __restrict__ WihTf, float* __restrict__ WihTr,
    float* __restrict__ WTf,   float* __restrict__ WTr,
    float* __restrict__ WfcT)
{
    __shared__ float tile[32][33];
    const int bx = blockIdx.x;
    const float* src; float* dst; int R, C, t;
    if (bx < 128)      { src = Wihf; dst = WihTf; R = 1024; C = 128; t = bx; }
    else if (bx < 256) { src = Wihr; dst = WihTr; R = 1024; C = 128; t = bx - 128; }
    else if (bx < 512) { src = Whhf; dst = WTf;   R = 1024; C = 256; t = bx - 256; }
    else if (bx < 768) { src = Whhr; dst = WTr;   R = 1024; C = 256; t = bx - 512; }
    else               { src = Wfc;  dst = WfcT;  R = 128;  C = 512; t = bx - 768; }
    const int tilesX = C / 32;
    const int c0 = (t % tilesX) * 32;
    const int r0 = (t / tilesX) * 32;
    const int tx = threadIdx.x;
    const int ty = threadIdx.y;
    #pragma unroll
    for (int i = ty; i < 32; i += 8)
        tile[i][tx] = src[(size_t)(r0 + i) * C + (c0 + tx)];
    __syncthreads();
    #pragma unroll
    for (int i = ty; i < 32; i += 8)
        dst[(size_t)(c0 + i) * R + (r0 + tx)] = tile[tx][i];
}

// ---------------------------------------------------------------------------
// K1: xW_d[(b,t)][gate] = x[b,t,:] @ W_ih_d.T   (no bias, no mask yet)
// ---------------------------------------------------------------------------
__global__ __launch_bounds__(256) void k1_xw(
    const float* __restrict__ x,
    const float* __restrict__ WihT_f, const float* __restrict__ WihT_r,
    float* __restrict__ xW_f, float* __restrict__ xW_r)
{
    __shared__ float xs[8 * kDIN];   // 4 KB
    const int tid = threadIdx.x;
    const int r0  = blockIdx.x * 8;
    const int gi  = tid * 4;

    ((float4*)xs)[tid] = ((const float4*)(x + (size_t)r0 * kDIN))[tid];
    __syncthreads();

    float accf[8][4], accr[8][4];
    #pragma unroll
    for (int s = 0; s < 8; ++s)
        #pragma unroll
        for (int q = 0; q < 4; ++q) { accf[s][q] = 0.f; accr[s][q] = 0.f; }

    #pragma unroll 2
    for (int k = 0; k < kDIN; ++k) {
        float4 wf = *(const float4*)(WihT_f + (size_t)k * kG4 + gi);
        float4 wr = *(const float4*)(WihT_r + (size_t)k * kG4 + gi);
        float wfa[4] = {wf.x, wf.y, wf.z, wf.w};
        float wra[4] = {wr.x, wr.y, wr.z, wr.w};
        #pragma unroll
        for (int s = 0; s < 8; ++s) {
            float xv = xs[s * kDIN + k];
            #pragma unroll
            for (int q = 0; q < 4; ++q) {
                accf[s][q] = fmaf(xv, wfa[q], accf[s][q]);
                accr[s][q] = fmaf(xv, wra[q], accr[s][q]);
            }
        }
    }

    #pragma unroll
    for (int s = 0; s < 8; ++s) {
        *(float4*)(xW_f + (size_t)(r0 + s) * kG4 + gi) =
            make_float4(accf[s][0], accf[s][1], accf[s][2], accf[s][3]);
        *(float4*)(xW_r + (size_t)(r0 + s) * kG4 + gi) =
            make_float4(accr[s][0], accr[s][1], accr[s][2], accr[s][3]);
    }
}

// ---------------------------------------------------------------------------
// K2: bidirectional LSTM recurrence, diagonal extraction.
// Grid: 512 blocks = dir(2) x n(32) x batch-tile(8).  512 threads/block.
// Each block runs ONE direction for 8 sequences: fwd n+1 steps or rev 32-n.
// GEMM phase: thread owns 2 adjacent gate columns (gi2 = tid*2), 8 seqs.
// Update phase: thread = (seq-half, hidden unit); carries c for 4 seqs.
// ---------------------------------------------------------------------------
__global__ __launch_bounds__(512) void k2_lstm(
    const float* __restrict__ mask,
    const float* __restrict__ xW_f, const float* __restrict__ xW_r,
    const float* __restrict__ WT_f, const float* __restrict__ WT_r,
    const float* __restrict__ b_f,  const float* __restrict__ b_r,
    float* __restrict__ y)
{
    __shared__ float h_lds[8 * kH];    // 8 KB
    __shared__ float g_lds[8 * kG4];   // 32 KB

    const int tid = threadIdx.x;
    const int bx  = blockIdx.x;
    const int dir = bx >> 8;                 // 0 fwd, 1 rev
    const int n   = (bx & 255) >> 3;         // 0..31
    const int b0  = (bx & 7) * 8;            // batch base
    const int gi2 = tid * 2;                 // 2 gate cols per thread

    const float* __restrict__ xW = dir ? xW_r : xW_f;
    const float* __restrict__ WT = dir ? WT_r : WT_f;
    const float* __restrict__ bb = dir ? b_r  : b_f;
    const float2 bias2 = *(const float2*)(bb + gi2);

    // update-phase identity
    const int hid = tid & 255;
    const int sh  = tid >> 8;                // 0..1 -> seqs sh*4..sh*4+3

    for (int i = tid; i < 8 * kH; i += 512) h_lds[i] = 0.f;
    float c[4] = {0.f, 0.f, 0.f, 0.f};
    __syncthreads();

    const int nsteps = dir ? (kN - n) : (n + 1);
    for (int it = 0; it < nsteps; ++it) {
        const int t = dir ? (kN - 1 - it) : it;

        // ---- GEMM phase: g = mask * xW + bias + h @ W_hh.T ----
        float acc[8][2];
        #pragma unroll
        for (int s = 0; s < 8; ++s) {
            const int   row = (b0 + s) * kN + t;
            const float m   = mask[(size_t)(b0 + s) * (kN * kN) + n * kN + t];
            float2 xv = *(const float2*)(xW + (size_t)row * kG4 + gi2);
            acc[s][0] = fmaf(m, xv.x, bias2.x);
            acc[s][1] = fmaf(m, xv.y, bias2.y);
        }

        for (int k0 = 0; k0 < kH; k0 += 8) {
            float2 w[8];
            #pragma unroll
            for (int kk = 0; kk < 8; ++kk)
                w[kk] = *(const float2*)(WT + (size_t)(k0 + kk) * kG4 + gi2);
            #pragma unroll
            for (int s = 0; s < 8; ++s) {
                float4 h0 = *(const float4*)(h_lds + s * kH + k0);
                float4 h1 = *(const float4*)(h_lds + s * kH + k0 + 4);
                float hv[8] = {h0.x, h0.y, h0.z, h0.w, h1.x, h1.y, h1.z, h1.w};
                #pragma unroll
                for (int kk = 0; kk < 8; ++kk) {
                    acc[s][0] = fmaf(hv[kk], w[kk].x, acc[s][0]);
                    acc[s][1] = fmaf(hv[kk], w[kk].y, acc[s][1]);
                }
            }
        }

        #pragma unroll
        for (int s = 0; s < 8; ++s)
            *(float2*)(g_lds + s * kG4 + gi2) = make_float2(acc[s][0], acc[s][1]);
        __syncthreads();

        // ---- update phase: 512 threads = 2 seq-halves x 256 hidden ----
        #pragma unroll
        for (int j = 0; j < 4; ++j) {
            const int s = sh * 4 + j;
            const float gI = g_lds[s * kG4 + hid];
            const float gF = g_lds[s * kG4 + kH + hid];
            const float gG = g_lds[s * kG4 + 2 * kH + hid];
            const float gO = g_lds[s * kG4 + 3 * kH + hid];
            const float ct = sigm(gF) * c[j] + sigm(gI) * tanhf(gG);
            c[j] = ct;
            const float hn = sigm(gO) * tanhf(ct);
            h_lds[s * kH + hid] = hn;
            if (t == n)
                y[((size_t)(b0 + s) * kN + n) * (2 * kH) + dir * kH + hid] = hn;
        }
        __syncthreads();
    }
}

// ---------------------------------------------------------------------------
// K3: out = relu(y @ W_fc.T + b_fc).  WfcT[k][dout] pre-transposed.
// ---------------------------------------------------------------------------
__global__ __launch_bounds__(256) void k3_out(
    const float* __restrict__ y, const float* __restrict__ WfcT,
    const float* __restrict__ b_fc, float* __restrict__ out)
{
    __shared__ float ys[8 * 2 * kH];   // 16 KB
    const int tid = threadIdx.x;
    const int r0  = blockIdx.x * 8;
    const int col = tid & 127;
    const int rh  = tid >> 7;

    for (int i = tid; i < 8 * 2 * kH / 4; i += 256)
        ((float4*)ys)[i] = ((const float4*)(y + (size_t)r0 * (2 * kH)))[i];
    __syncthreads();

    float acc[4] = {0.f, 0.f, 0.f, 0.f};
    #pragma unroll 4
    for (int k = 0; k < 2 * kH; ++k) {
        const float w = WfcT[(size_t)k * kDOUT + col];
        #pragma unroll
        for (int j = 0; j < 4; ++j)
            acc[j] = fmaf(ys[(rh * 4 + j) * (2 * kH) + k], w, acc[j]);
    }

    const float bias = b_fc[col];
    #pragma unroll
    for (int j = 0; j < 4; ++j) {
        const int row = r0 + rh * 4 + j;
        out[(size_t)row * kDOUT + col] = fmaxf(acc[j] + bias, 0.f);
    }
}

// ---------------------------------------------------------------------------
extern "C" void kernel_launch(void* const* d_in, const int* in_sizes, int n_in,
                              void* d_out, int out_size, void* d_ws, size_t ws_size,
                              hipStream_t stream) {
    const float* x      = (const float*)d_in[0];
    const float* mask   = (const float*)d_in[1];
    const float* W_ih_f = (const float*)d_in[2];
    const float* W_hh_f = (const float*)d_in[3];
    const float* b_f    = (const float*)d_in[4];
    const float* W_ih_r = (const float*)d_in[5];
    const float* W_hh_r = (const float*)d_in[6];
    const float* b_r    = (const float*)d_in[7];
    const float* W_fc   = (const float*)d_in[8];
    const float* b_fc   = (const float*)d_in[9];
    float* out = (float*)d_out;

    float* ws     = (float*)d_ws;
    float* WihT_f = ws;                    // 128*1024
    float* WihT_r = WihT_f + 131072;       // 128*1024
    float* WT_f   = WihT_r + 131072;       // 256*1024
    float* WT_r   = WT_f   + 262144;       // 256*1024
    float* WfcT   = WT_r   + 262144;       // 512*128
    float* xW_f   = WfcT   + 65536;        // 2048*1024
    float* xW_r   = xW_f   + 2097152;      // 2048*1024
    float* yb     = xW_r   + 2097152;      // 2048*512

    prep_transpose<<<832, dim3(32, 8), 0, stream>>>(
        W_ih_f, W_ih_r, W_hh_f, W_hh_r, W_fc,
        WihT_f, WihT_r, WT_f, WT_r, WfcT);

    k1_xw<<<kBN / 8, 256, 0, stream>>>(x, WihT_f, WihT_r, xW_f, xW_r);
    k2_lstm<<<kN * 8 * 2, 512, 0, stream>>>(mask, xW_f, xW_r, WT_f, WT_r, b_f, b_r, yb);
    k3_out<<<kBN / 8, 256, 0, stream>>>(yb, WfcT, b_fc, out);
}

// Round 3
// 696.914 us; speedup vs baseline: 2.0056x; 1.1332x over previous
//
#include <hip/hip_runtime.h>
#include <math.h>

// Problem constants
constexpr int kB    = 64;
constexpr int kN    = 32;
constexpr int kDIN  = 128;
constexpr int kH    = 256;
constexpr int kG4   = 1024;   // 4*H
constexpr int kDOUT = 128;
constexpr int kBN   = 2048;   // B*N

typedef __attribute__((ext_vector_type(8))) short bf16x8;
typedef __attribute__((ext_vector_type(4))) float f32x4;

__device__ __forceinline__ float sigm(float x) {
    return 1.0f / (1.0f + expf(-x));
}

// fp32 -> bf16 bits, round-to-nearest-even
__device__ __forceinline__ short f2bf(float f) {
    union { float f; unsigned u; } v; v.f = f;
    unsigned r = v.u + 0x7fffu + ((v.u >> 16) & 1u);
    return (short)(r >> 16);
}

// ---------------------------------------------------------------------------
// K0 prep (one launch):
//   blocks [0,128)   transpose W_ih_f (1024x128) -> WihT_f [k][gate]
//   blocks [128,256) transpose W_ih_r            -> WihT_r
//   blocks [256,320) transpose W_fc   (128x512)  -> WfcT   [k][dout]
//   blocks [320,576) convert W_hh_f/W_hh_r to bf16, ORIGINAL [gate][k] layout
// ---------------------------------------------------------------------------
__global__ __launch_bounds__(256) void prep_k(
    const float* __restrict__ Wihf, const float* __restrict__ Wihr,
    const float* __restrict__ Whhf, const float* __restrict__ Whhr,
    const float* __restrict__ Wfc,
    float* __restrict__ WihTf, float* __restrict__ WihTr,
    float* __restrict__ WfcT,
    short* __restrict__ Wbf_f, short* __restrict__ Wbf_r)
{
    const int bx = blockIdx.x;
    if (bx >= 320) {
        // convert: 2 x 262144 bf16 elements, 256 blocks x 2048 elems
        const int cb   = bx - 320;                 // 0..255
        const int half = cb >> 7;                  // 0: fwd, 1: rev
        const float* src = half ? Whhr : Whhf;
        short*       dst = half ? Wbf_r : Wbf_f;
        const int base = ((cb & 127) * 256 + threadIdx.x) * 8;  // wrong if ty used
        // 256 threads x 8 elems = 2048 per block
        const int tid = threadIdx.y * 32 + threadIdx.x;
        const int b2  = (cb & 127) * 2048 + tid * 8;
        (void)base;
        #pragma unroll
        for (int j = 0; j < 8; ++j) dst[b2 + j] = f2bf(src[b2 + j]);
        return;
    }
    __shared__ float tile[32][33];
    const float* src; float* dst; int R, C, t;
    if (bx < 128)      { src = Wihf; dst = WihTf; R = 1024; C = 128; t = bx; }
    else if (bx < 256) { src = Wihr; dst = WihTr; R = 1024; C = 128; t = bx - 128; }
    else               { src = Wfc;  dst = WfcT;  R = 128;  C = 512; t = bx - 256; }
    const int tilesX = C / 32;
    const int c0 = (t % tilesX) * 32;
    const int r0 = (t / tilesX) * 32;
    const int tx = threadIdx.x;
    const int ty = threadIdx.y;
    #pragma unroll
    for (int i = ty; i < 32; i += 8)
        tile[i][tx] = src[(size_t)(r0 + i) * C + (c0 + tx)];
    __syncthreads();
    #pragma unroll
    for (int i = ty; i < 32; i += 8)
        dst[(size_t)(c0 + i) * R + (r0 + tx)] = tile[tx][i];
}

// ---------------------------------------------------------------------------
// K1: xW_d[(b,t)][gate] = x[b,t,:] @ W_ih_d.T  (fp32, unchanged)
// ---------------------------------------------------------------------------
__global__ __launch_bounds__(256) void k1_xw(
    const float* __restrict__ x,
    const float* __restrict__ WihT_f, const float* __restrict__ WihT_r,
    float* __restrict__ xW_f, float* __restrict__ xW_r)
{
    __shared__ float xs[8 * kDIN];
    const int tid = threadIdx.x;
    const int r0  = blockIdx.x * 8;
    const int gi  = tid * 4;

    ((float4*)xs)[tid] = ((const float4*)(x + (size_t)r0 * kDIN))[tid];
    __syncthreads();

    float accf[8][4], accr[8][4];
    #pragma unroll
    for (int s = 0; s < 8; ++s)
        #pragma unroll
        for (int q = 0; q < 4; ++q) { accf[s][q] = 0.f; accr[s][q] = 0.f; }

    #pragma unroll 2
    for (int k = 0; k < kDIN; ++k) {
        float4 wf = *(const float4*)(WihT_f + (size_t)k * kG4 + gi);
        float4 wr = *(const float4*)(WihT_r + (size_t)k * kG4 + gi);
        float wfa[4] = {wf.x, wf.y, wf.z, wf.w};
        float wra[4] = {wr.x, wr.y, wr.z, wr.w};
        #pragma unroll
        for (int s = 0; s < 8; ++s) {
            float xv = xs[s * kDIN + k];
            #pragma unroll
            for (int q = 0; q < 4; ++q) {
                accf[s][q] = fmaf(xv, wfa[q], accf[s][q]);
                accr[s][q] = fmaf(xv, wra[q], accr[s][q]);
            }
        }
    }

    #pragma unroll
    for (int s = 0; s < 8; ++s) {
        *(float4*)(xW_f + (size_t)(r0 + s) * kG4 + gi) =
            make_float4(accf[s][0], accf[s][1], accf[s][2], accf[s][3]);
        *(float4*)(xW_r + (size_t)(r0 + s) * kG4 + gi) =
            make_float4(accr[s][0], accr[s][1], accr[s][2], accr[s][3]);
    }
}

// ---------------------------------------------------------------------------
// K2: bidirectional LSTM recurrence via bf16 MFMA, fp32 accumulate.
// Grid: 256 blocks = n(32) x batch-tile(8).  512 threads = 8 waves.
// Block does fwd (n+1 steps) then rev (32-n steps): 33 uniform steps.
// M=16 MFMA rows: rows 0..7 = real batch seqs, rows 8..15 stay zero.
// Wave w owns h-units [32w,32w+32) = 8 gate tiles (4 gates x 2 halves),
// so all 4 gates of a unit are in the same lane -> in-register epilogue.
// h: double-buffered bf16 LDS, row stride 264 (bank spread, 16B aligned).
// W_hh streamed from L2 as B-frags: lane reads Wbf[gate=nb+l15][k0+quad*8..+7].
// ---------------------------------------------------------------------------
__global__ __launch_bounds__(512) void k2_lstm(
    const float* __restrict__ mask,
    const float* __restrict__ xW_f, const float* __restrict__ xW_r,
    const short* __restrict__ Wbf_f, const short* __restrict__ Wbf_r,
    const float* __restrict__ b_f,  const float* __restrict__ b_r,
    float* __restrict__ y)
{
    constexpr int HP = 264;                    // padded row, elements
    __shared__ short h_lds[2][16][HP];         // 16.5 KB

    const int tid  = threadIdx.x;
    const int wave = tid >> 6;
    const int lane = tid & 63;
    const int quad = lane >> 4;
    const int l15  = lane & 15;
    const int n_seq = blockIdx.x >> 3;
    const int b0    = (blockIdx.x & 7) * 8;

    // zero both h buffers fully (rows 8..15 stay zero forever)
    for (int i = tid; i < 2 * 16 * HP; i += 512) ((short*)h_lds)[i] = 0;

    // tile n-bases: tau = g*2+q  -> gate g, half q
    int nb[8];
    #pragma unroll
    for (int g = 0; g < 4; ++g)
        #pragma unroll
        for (int q = 0; q < 2; ++q)
            nb[g * 2 + q] = g * 256 + wave * 32 + q * 16;

    for (int dir = 0; dir < 2; ++dir) {
        const float* __restrict__ xW = dir ? xW_r : xW_f;
        const short* __restrict__ W  = dir ? Wbf_r : Wbf_f;
        const float* __restrict__ bb = dir ? b_r : b_f;

        float bias[8];
        #pragma unroll
        for (int tau = 0; tau < 8; ++tau) bias[tau] = bb[nb[tau] + l15];

        __syncthreads();   // prior-dir reads done before re-zero
        for (int i = tid; i < 8 * HP; i += 512) (&h_lds[0][0][0])[i] = 0;
        float c[8];
        #pragma unroll
        for (int i = 0; i < 8; ++i) c[i] = 0.f;
        __syncthreads();

        // per-lane W base pointers (k-offset quad*8 folded in)
        const short* wp[8];
        #pragma unroll
        for (int tau = 0; tau < 8; ++tau)
            wp[tau] = W + (size_t)(nb[tau] + l15) * kH + quad * 8;

        const int nsteps = dir ? (kN - n_seq) : (n_seq + 1);
        int cur = 0;
        for (int it = 0; it < nsteps; ++it) {
            const int t = dir ? (kN - 1 - it) : it;

            // A-fragments: h rows l15, k = kt*32 + quad*8 .. +7
            bf16x8 a[8];
            #pragma unroll
            for (int kt = 0; kt < 8; ++kt)
                a[kt] = *(const bf16x8*)&h_lds[cur][l15][kt * 32 + quad * 8];

            // acc init: mask*xW + bias (only real rows m=quad*4+r < 8)
            f32x4 acc[8];
            if (quad < 2) {
                float mk[4]; int rowb[4];
                #pragma unroll
                for (int r = 0; r < 4; ++r) {
                    const int m = quad * 4 + r;
                    mk[r]   = mask[(size_t)(b0 + m) * (kN * kN) + n_seq * kN + t];
                    rowb[r] = ((b0 + m) * kN + t) * kG4 + l15;
                }
                #pragma unroll
                for (int tau = 0; tau < 8; ++tau)
                    #pragma unroll
                    for (int r = 0; r < 4; ++r)
                        acc[tau][r] = fmaf(mk[r], xW[rowb[r] + nb[tau]], bias[tau]);
            } else {
                #pragma unroll
                for (int tau = 0; tau < 8; ++tau)
                    #pragma unroll
                    for (int r = 0; r < 4; ++r) acc[tau][r] = 0.f;
            }

            // K loop: 8 k-tiles x 8 n-tiles MFMA, W streamed from L2
            #pragma unroll
            for (int kt = 0; kt < 8; ++kt) {
                #pragma unroll
                for (int tau = 0; tau < 8; ++tau) {
                    bf16x8 bf = *(const bf16x8*)(wp[tau] + kt * 32);
                    acc[tau] = __builtin_amdgcn_mfma_f32_16x16x32_bf16(
                        a[kt], bf, acc[tau], 0, 0, 0);
                }
            }

            // epilogue: lane holds gates (g, q, r) for unit u, seq m
            const int nxt = cur ^ 1;
            if (quad < 2) {
                #pragma unroll
                for (int q = 0; q < 2; ++q)
                    #pragma unroll
                    for (int r = 0; r < 4; ++r) {
                        const int m  = quad * 4 + r;
                        const int u  = wave * 32 + q * 16 + l15;
                        const int ci = q * 4 + r;
                        const float gI = acc[0 + q][r];
                        const float gF = acc[2 + q][r];
                        const float gG = acc[4 + q][r];
                        const float gO = acc[6 + q][r];
                        const float ct = sigm(gF) * c[ci] + sigm(gI) * tanhf(gG);
                        c[ci] = ct;
                        const float hn = sigm(gO) * tanhf(ct);
                        h_lds[nxt][m][u] = f2bf(hn);
                        if (t == n_seq)
                            y[((size_t)(b0 + m) * kN + n_seq) * (2 * kH)
                              + dir * kH + u] = hn;
                    }
            }
            __syncthreads();
            cur = nxt;
        }
    }
}

// ---------------------------------------------------------------------------
// K3: out = relu(y @ W_fc.T + b_fc).  (fp32, unchanged)
// ---------------------------------------------------------------------------
__global__ __launch_bounds__(256) void k3_out(
    const float* __restrict__ y, const float* __restrict__ WfcT,
    const float* __restrict__ b_fc, float* __restrict__ out)
{
    __shared__ float ys[8 * 2 * kH];
    const int tid = threadIdx.x;
    const int r0  = blockIdx.x * 8;
    const int col = tid & 127;
    const int rh  = tid >> 7;

    for (int i = tid; i < 8 * 2 * kH / 4; i += 256)
        ((float4*)ys)[i] = ((const float4*)(y + (size_t)r0 * (2 * kH)))[i];
    __syncthreads();

    float acc[4] = {0.f, 0.f, 0.f, 0.f};
    #pragma unroll 4
    for (int k = 0; k < 2 * kH; ++k) {
        const float w = WfcT[(size_t)k * kDOUT + col];
        #pragma unroll
        for (int j = 0; j < 4; ++j)
            acc[j] = fmaf(ys[(rh * 4 + j) * (2 * kH) + k], w, acc[j]);
    }

    const float bias = b_fc[col];
    #pragma unroll
    for (int j = 0; j < 4; ++j) {
        const int row = r0 + rh * 4 + j;
        out[(size_t)row * kDOUT + col] = fmaxf(acc[j] + bias, 0.f);
    }
}

// ---------------------------------------------------------------------------
extern "C" void kernel_launch(void* const* d_in, const int* in_sizes, int n_in,
                              void* d_out, int out_size, void* d_ws, size_t ws_size,
                              hipStream_t stream) {
    const float* x      = (const float*)d_in[0];
    const float* mask   = (const float*)d_in[1];
    const float* W_ih_f = (const float*)d_in[2];
    const float* W_hh_f = (const float*)d_in[3];
    const float* b_f    = (const float*)d_in[4];
    const float* W_ih_r = (const float*)d_in[5];
    const float* W_hh_r = (const float*)d_in[6];
    const float* b_r    = (const float*)d_in[7];
    const float* W_fc   = (const float*)d_in[8];
    const float* b_fc   = (const float*)d_in[9];
    float* out = (float*)d_out;

    float* ws     = (float*)d_ws;
    float* WihT_f = ws;                    // 128*1024 f
    float* WihT_r = WihT_f + 131072;       // 128*1024 f
    float* WfcT   = WihT_r + 131072;       // 512*128 f
    short* Wbf_f  = (short*)(WfcT + 65536);      // 1024*256 bf16
    short* Wbf_r  = Wbf_f + 262144;              // 1024*256 bf16
    float* xW_f   = (float*)(Wbf_r + 262144);    // 2048*1024 f
    float* xW_r   = xW_f + 2097152;        // 2048*1024 f
    float* yb     = xW_r + 2097152;        // 2048*512 f

    prep_k<<<576, dim3(32, 8), 0, stream>>>(
        W_ih_f, W_ih_r, W_hh_f, W_hh_r, W_fc,
        WihT_f, WihT_r, WfcT, Wbf_f, Wbf_r);

    k1_xw<<<kBN / 8, 256, 0, stream>>>(x, WihT_f, WihT_r, xW_f, xW_r);
    k2_lstm<<<kN * 8, 512, 0, stream>>>(mask, xW_f, xW_r, Wbf_f, Wbf_r, b_f, b_r, yb);
    k3_out<<<kBN / 8, 256, 0, stream>>>(yb, WfcT, b_fc, out);
}

// Round 4
// 610.815 us; speedup vs baseline: 2.2883x; 1.1410x over previous
//
#include <hip/hip_runtime.h>
#include <math.h>

// Problem constants
constexpr int kB    = 64;
constexpr int kN    = 32;
constexpr int kDIN  = 128;
constexpr int kH    = 256;
constexpr int kG4   = 1024;   // 4*H
constexpr int kDOUT = 128;
constexpr int kBN   = 2048;   // B*N

typedef __attribute__((ext_vector_type(8))) short bf16x8;
typedef __attribute__((ext_vector_type(4))) float f32x4;

__device__ __forceinline__ float sigm(float x) {
    return 1.0f / (1.0f + expf(-x));
}

// fp32 -> bf16 bits, round-to-nearest-even
__device__ __forceinline__ short f2bf(float f) {
    union { float f; unsigned u; } v; v.f = f;
    unsigned r = v.u + 0x7fffu + ((v.u >> 16) & 1u);
    return (short)(r >> 16);
}

// ---------------------------------------------------------------------------
// K0 prep (one launch):
//   blocks [0,128)   transpose W_ih_f (1024x128) -> WihT_f [k][gate]
//   blocks [128,256) transpose W_ih_r            -> WihT_r
//   blocks [256,320) transpose W_fc   (128x512)  -> WfcT   [k][dout]
//   blocks [320,576) convert W_hh_f/W_hh_r to bf16, ORIGINAL [gate][k] layout
// ---------------------------------------------------------------------------
__global__ __launch_bounds__(256) void prep_k(
    const float* __restrict__ Wihf, const float* __restrict__ Wihr,
    const float* __restrict__ Whhf, const float* __restrict__ Whhr,
    const float* __restrict__ Wfc,
    float* __restrict__ WihTf, float* __restrict__ WihTr,
    float* __restrict__ WfcT,
    short* __restrict__ Wbf_f, short* __restrict__ Wbf_r)
{
    const int bx = blockIdx.x;
    if (bx >= 320) {
        const int cb   = bx - 320;                 // 0..255
        const int half = cb >> 7;                  // 0: fwd, 1: rev
        const float* src = half ? Whhr : Whhf;
        short*       dst = half ? Wbf_r : Wbf_f;
        const int tid = threadIdx.y * 32 + threadIdx.x;
        const int b2  = (cb & 127) * 2048 + tid * 8;
        #pragma unroll
        for (int j = 0; j < 8; ++j) dst[b2 + j] = f2bf(src[b2 + j]);
        return;
    }
    __shared__ float tile[32][33];
    const float* src; float* dst; int R, C, t;
    if (bx < 128)      { src = Wihf; dst = WihTf; R = 1024; C = 128; t = bx; }
    else if (bx < 256) { src = Wihr; dst = WihTr; R = 1024; C = 128; t = bx - 128; }
    else               { src = Wfc;  dst = WfcT;  R = 128;  C = 512; t = bx - 256; }
    const int tilesX = C / 32;
    const int c0 = (t % tilesX) * 32;
    const int r0 = (t / tilesX) * 32;
    const int tx = threadIdx.x;
    const int ty = threadIdx.y;
    #pragma unroll
    for (int i = ty; i < 32; i += 8)
        tile[i][tx] = src[(size_t)(r0 + i) * C + (c0 + tx)];
    __syncthreads();
    #pragma unroll
    for (int i = ty; i < 32; i += 8)
        dst[(size_t)(c0 + i) * R + (r0 + tx)] = tile[tx][i];
}

// ---------------------------------------------------------------------------
// K1: xW_d[(b,t)][gate] = x[b,t,:] @ W_ih_d.T  (fp32)
// ---------------------------------------------------------------------------
__global__ __launch_bounds__(256) void k1_xw(
    const float* __restrict__ x,
    const float* __restrict__ WihT_f, const float* __restrict__ WihT_r,
    float* __restrict__ xW_f, float* __restrict__ xW_r)
{
    __shared__ float xs[8 * kDIN];
    const int tid = threadIdx.x;
    const int r0  = blockIdx.x * 8;
    const int gi  = tid * 4;

    ((float4*)xs)[tid] = ((const float4*)(x + (size_t)r0 * kDIN))[tid];
    __syncthreads();

    float accf[8][4], accr[8][4];
    #pragma unroll
    for (int s = 0; s < 8; ++s)
        #pragma unroll
        for (int q = 0; q < 4; ++q) { accf[s][q] = 0.f; accr[s][q] = 0.f; }

    #pragma unroll 2
    for (int k = 0; k < kDIN; ++k) {
        float4 wf = *(const float4*)(WihT_f + (size_t)k * kG4 + gi);
        float4 wr = *(const float4*)(WihT_r + (size_t)k * kG4 + gi);
        float wfa[4] = {wf.x, wf.y, wf.z, wf.w};
        float wra[4] = {wr.x, wr.y, wr.z, wr.w};
        #pragma unroll
        for (int s = 0; s < 8; ++s) {
            float xv = xs[s * kDIN + k];
            #pragma unroll
            for (int q = 0; q < 4; ++q) {
                accf[s][q] = fmaf(xv, wfa[q], accf[s][q]);
                accr[s][q] = fmaf(xv, wra[q], accr[s][q]);
            }
        }
    }

    #pragma unroll
    for (int s = 0; s < 8; ++s) {
        *(float4*)(xW_f + (size_t)(r0 + s) * kG4 + gi) =
            make_float4(accf[s][0], accf[s][1], accf[s][2], accf[s][3]);
        *(float4*)(xW_r + (size_t)(r0 + s) * kG4 + gi) =
            make_float4(accr[s][0], accr[s][1], accr[s][2], accr[s][3]);
    }
}

// ---------------------------------------------------------------------------
// K2: bidirectional LSTM recurrence via bf16 MFMA, fp32 accumulate.
// Grid: 256 blocks = dir(2) x n(32) x b-tile4(4 tiles of 16 batches).
// 512 threads = 8 waves.  One direction per block: fwd n+1 / rev 32-n steps.
// M=16 = 16 REAL batch rows (no padding waste).
// Wave w owns gate cols {g*256 + 32w + q*16 + l15}: all 4 gates of units
// [32w,32w+32) -> in-register LSTM epilogue, c-state in VGPRs.
// xW + mask for step t+1 prefetched into registers during step t's MFMA.
// W_hh slice kt={0,1} persisted in VGPRs (64 regs); kt=2..7 streamed from L2.
// h double-buffered bf16 in LDS.
// ---------------------------------------------------------------------------
__global__ __launch_bounds__(512) void k2_lstm(
    const float* __restrict__ mask,
    const float* __restrict__ xW_f, const float* __restrict__ xW_r,
    const short* __restrict__ Wbf_f, const short* __restrict__ Wbf_r,
    const float* __restrict__ b_f,  const float* __restrict__ b_r,
    float* __restrict__ y)
{
    constexpr int HP = 272;                    // padded row (shorts), 544 B
    __shared__ short h_lds[2][16][HP];         // 17.4 KB

    const int tid  = threadIdx.x;
    const int wave = tid >> 6;
    const int lane = tid & 63;
    const int quad = lane >> 4;
    const int l15  = lane & 15;

    const int bx    = blockIdx.x;
    const int dir   = bx >> 7;                 // 0 fwd, 1 rev
    const int rest  = bx & 127;
    const int n_seq = rest >> 2;               // 0..31
    const int b0    = (rest & 3) * 16;         // batch base (16 per tile)

    const float* __restrict__ xW = dir ? xW_r : xW_f;
    const short* __restrict__ W  = dir ? Wbf_r : Wbf_f;
    const float* __restrict__ bb = dir ? b_r : b_f;

    // tile n-bases: tau = g*2+q -> gate g, half q
    int nb[8];
    #pragma unroll
    for (int g = 0; g < 4; ++g)
        #pragma unroll
        for (int q = 0; q < 2; ++q)
            nb[g * 2 + q] = g * 256 + wave * 32 + q * 16;

    float bias[8];
    #pragma unroll
    for (int tau = 0; tau < 8; ++tau) bias[tau] = bb[nb[tau] + l15];

    // per-lane W base pointers (k-offset quad*8 folded in)
    const short* wp[8];
    #pragma unroll
    for (int tau = 0; tau < 8; ++tau)
        wp[tau] = W + (size_t)(nb[tau] + l15) * kH + quad * 8;

    // persist kt = 0,1 of the W slice in registers (64 VGPRs)
    bf16x8 wreg[8][2];
    #pragma unroll
    for (int tau = 0; tau < 8; ++tau)
        #pragma unroll
        for (int k2 = 0; k2 < 2; ++k2)
            wreg[tau][k2] = *(const bf16x8*)(wp[tau] + k2 * 32);

    // zero h (both buffers), zero c
    for (int i = tid; i < 2 * 16 * HP; i += 512) ((short*)h_lds)[i] = 0;
    float c[8];
    #pragma unroll
    for (int i = 0; i < 8; ++i) c[i] = 0.f;
    __syncthreads();

    const int nsteps = dir ? (kN - n_seq) : (n_seq + 1);
    const int t0     = dir ? (kN - 1) : 0;

    // initial prefetch of xW + mask for t0
    float xw0[8][4];
    float mk0[4];
    {
        #pragma unroll
        for (int r = 0; r < 4; ++r) {
            const int m = quad * 4 + r;
            mk0[r] = mask[(size_t)(b0 + m) * (kN * kN) + n_seq * kN + t0];
            const int rowb = ((b0 + m) * kN + t0) * kG4 + l15;
            #pragma unroll
            for (int tau = 0; tau < 8; ++tau)
                xw0[tau][r] = xW[rowb + nb[tau]];
        }
    }

    int cur = 0;
    for (int it = 0; it < nsteps; ++it) {
        const int t = dir ? (kN - 1 - it) : it;

        // acc init from prefetched xW/mask
        f32x4 acc[8];
        #pragma unroll
        for (int tau = 0; tau < 8; ++tau)
            #pragma unroll
            for (int r = 0; r < 4; ++r)
                acc[tau][r] = fmaf(mk0[r], xw0[tau][r], bias[tau]);

        // prefetch next step's xW/mask (loads overlap the K-loop below)
        {
            const int tn = (it + 1 < nsteps) ? (dir ? t - 1 : t + 1) : t;
            #pragma unroll
            for (int r = 0; r < 4; ++r) {
                const int m = quad * 4 + r;
                mk0[r] = mask[(size_t)(b0 + m) * (kN * kN) + n_seq * kN + tn];
                const int rowb = ((b0 + m) * kN + tn) * kG4 + l15;
                #pragma unroll
                for (int tau = 0; tau < 8; ++tau)
                    xw0[tau][r] = xW[rowb + nb[tau]];
            }
        }

        // K loop: kt 0,1 from registers; kt 2..7 streamed from L2
        #pragma unroll
        for (int kt = 0; kt < 8; ++kt) {
            const bf16x8 a = *(const bf16x8*)&h_lds[cur][l15][kt * 32 + quad * 8];
            #pragma unroll
            for (int tau = 0; tau < 8; ++tau) {
                bf16x8 bfr;
                if (kt < 2) bfr = wreg[tau][kt];
                else        bfr = *(const bf16x8*)(wp[tau] + kt * 32);
                acc[tau] = __builtin_amdgcn_mfma_f32_16x16x32_bf16(
                    a, bfr, acc[tau], 0, 0, 0);
            }
        }

        // epilogue: lane holds gates (g,q,r) for unit u, batch-row m
        const int nxt = cur ^ 1;
        #pragma unroll
        for (int q = 0; q < 2; ++q)
            #pragma unroll
            for (int r = 0; r < 4; ++r) {
                const int m  = quad * 4 + r;
                const int u  = wave * 32 + q * 16 + l15;
                const int ci = q * 4 + r;
                const float gI = acc[0 + q][r];
                const float gF = acc[2 + q][r];
                const float gG = acc[4 + q][r];
                const float gO = acc[6 + q][r];
                const float ct = sigm(gF) * c[ci] + sigm(gI) * tanhf(gG);
                c[ci] = ct;
                const float hn = sigm(gO) * tanhf(ct);
                h_lds[nxt][m][u] = f2bf(hn);
                if (t == n_seq)
                    y[((size_t)(b0 + m) * kN + n_seq) * (2 * kH)
                      + dir * kH + u] = hn;
            }
        __syncthreads();
        cur = nxt;
    }
}

// ---------------------------------------------------------------------------
// K3: out = relu(y @ W_fc.T + b_fc).
// ---------------------------------------------------------------------------
__global__ __launch_bounds__(256) void k3_out(
    const float* __restrict__ y, const float* __restrict__ WfcT,
    const float* __restrict__ b_fc, float* __restrict__ out)
{
    __shared__ float ys[8 * 2 * kH];
    const int tid = threadIdx.x;
    const int r0  = blockIdx.x * 8;
    const int col = tid & 127;
    const int rh  = tid >> 7;

    for (int i = tid; i < 8 * 2 * kH / 4; i += 256)
        ((float4*)ys)[i] = ((const float4*)(y + (size_t)r0 * (2 * kH)))[i];
    __syncthreads();

    float acc[4] = {0.f, 0.f, 0.f, 0.f};
    #pragma unroll 4
    for (int k = 0; k < 2 * kH; ++k) {
        const float w = WfcT[(size_t)k * kDOUT + col];
        #pragma unroll
        for (int j = 0; j < 4; ++j)
            acc[j] = fmaf(ys[(rh * 4 + j) * (2 * kH) + k], w, acc[j]);
    }

    const float bias = b_fc[col];
    #pragma unroll
    for (int j = 0; j < 4; ++j) {
        const int row = r0 + rh * 4 + j;
        out[(size_t)row * kDOUT + col] = fmaxf(acc[j] + bias, 0.f);
    }
}

// ---------------------------------------------------------------------------
extern "C" void kernel_launch(void* const* d_in, const int* in_sizes, int n_in,
                              void* d_out, int out_size, void* d_ws, size_t ws_size,
                              hipStream_t stream) {
    const float* x      = (const float*)d_in[0];
    const float* mask   = (const float*)d_in[1];
    const float* W_ih_f = (const float*)d_in[2];
    const float* W_hh_f = (const float*)d_in[3];
    const float* b_f    = (const float*)d_in[4];
    const float* W_ih_r = (const float*)d_in[5];
    const float* W_hh_r = (const float*)d_in[6];
    const float* b_r    = (const float*)d_in[7];
    const float* W_fc   = (const float*)d_in[8];
    const float* b_fc   = (const float*)d_in[9];
    float* out = (float*)d_out;

    float* ws     = (float*)d_ws;
    float* WihT_f = ws;                    // 128*1024 f
    float* WihT_r = WihT_f + 131072;       // 128*1024 f
    float* WfcT   = WihT_r + 131072;       // 512*128 f
    short* Wbf_f  = (short*)(WfcT + 65536);      // 1024*256 bf16
    short* Wbf_r  = Wbf_f + 262144;              // 1024*256 bf16
    float* xW_f   = (float*)(Wbf_r + 262144);    // 2048*1024 f
    float* xW_r   = xW_f + 2097152;        // 2048*1024 f
    float* yb     = xW_r + 2097152;        // 2048*512 f

    prep_k<<<576, dim3(32, 8), 0, stream>>>(
        W_ih_f, W_ih_r, W_hh_f, W_hh_r, W_fc,
        WihT_f, WihT_r, WfcT, Wbf_f, Wbf_r);

    k1_xw<<<kBN / 8, 256, 0, stream>>>(x, WihT_f, WihT_r, xW_f, xW_r);
    k2_lstm<<<256, 512, 0, stream>>>(mask, xW_f, xW_r, Wbf_f, Wbf_r, b_f, b_r, yb);
    k3_out<<<kBN / 8, 256, 0, stream>>>(yb, WfcT, b_fc, out);
}